// Round 1
// baseline (566.397 us; speedup 1.0000x reference)
//
#include <hip/hip_runtime.h>
#include <hip/hip_bf16.h>

#define NN 10000     // nodes
#define NE 640000    // edges
#define NG 64        // graphs
#define NF 128       // feature dim (both layers)
#define NC 10        // classes

// ---------------- ws layout (bytes) ----------------
// 0        flags (2 ints, written every launch)       16
// 16       deg   (10000 int)                          40000   } zero
// 40016    sums  (64*128 f32)                         32768   } region
// 72784    cnt   (64 f32)                             256     } 73024 B
// 73040    csr_off (10001 int)                        40016
// 113056   csr_pos (10000 int)                        40000
// 153056   dinv  (10000 f32)                          40000
// 193056   csr_src (640000 int)                       2560000
// 2753056  csr_w  (640000 f32)                        2560000
// 5313056  bufA  (10000*128 f32)                      5120000
// 10433056 bufB  (10000*128 f32)                      5120000
// total ~15.6 MB

// Detect whether the integer inputs are int64 (JAX x64 on) or int32 (default).
// For int64 little-endian, every odd 32-bit word is the (zero) high half.
__global__ void k_detect(const int* ei_w, const int* batch_w, int* flags) {
    __shared__ int nz[2];
    int tid = threadIdx.x;
    if (tid < 2) nz[tid] = 0;
    __syncthreads();
    // edge_index: sample element idx e in [0, 640000); word 2e+1 < 1280000
    // (safe even if the buffer is int32: 2*NE int32 words exist).
    for (int k = tid; k < 2048; k += 256) {
        long e = (long)k * 639999L / 2047L;
        if (ei_w[2 * e + 1] != 0) nz[0] = 1;
    }
    // batch: 10000 elements; restrict words to < 10000 (int32-size safe).
    for (int k = tid; k < 2048; k += 256) {
        long e = (long)k * 4999L / 2047L;
        if (batch_w[2 * e + 1] != 0) nz[1] = 1;
    }
    __syncthreads();
    if (tid == 0) { flags[0] = nz[0] ? 0 : 1; flags[1] = nz[1] ? 0 : 1; }
}

__device__ __forceinline__ int ld_idx(const void* p, long i, int is64) {
    return is64 ? (int)((const long long*)p)[i] : ((const int*)p)[i];
}

__global__ void k_degree(const void* __restrict__ ei, const int* __restrict__ flags,
                         int* __restrict__ deg) {
    int e = blockIdx.x * blockDim.x + threadIdx.x;
    if (e >= NE) return;
    int is64 = flags[0];
    int dst = ld_idx(ei, (long)NE + e, is64);
    atomicAdd(&deg[dst], 1);
}

// Single-block exclusive scan of deg -> csr_off / csr_pos; also dinv = rsqrt(deg+1)
__global__ __launch_bounds__(1024) void k_scan(const int* __restrict__ deg,
                                               int* __restrict__ off, int* __restrict__ pos,
                                               float* __restrict__ dinv) {
    __shared__ int part[1024];
    int tid = threadIdx.x;
    const int CH = 10;              // 1024*10 >= 10000
    int base = tid * CH;
    int s = 0;
#pragma unroll
    for (int i = 0; i < CH; i++) { int id = base + i; if (id < NN) s += deg[id]; }
    part[tid] = s;
    __syncthreads();
    for (int o = 1; o < 1024; o <<= 1) {
        int add = (tid >= o) ? part[tid - o] : 0;
        __syncthreads();
        part[tid] += add;
        __syncthreads();
    }
    int run = (tid > 0) ? part[tid - 1] : 0;
#pragma unroll
    for (int i = 0; i < CH; i++) {
        int id = base + i;
        if (id < NN) { off[id] = run; pos[id] = run; run += deg[id]; }
    }
    if (tid == 0) off[NN] = part[1023];
    for (int id = tid; id < NN; id += 1024)
        dinv[id] = rsqrtf((float)deg[id] + 1.0f);
}

__global__ void k_fill(const void* __restrict__ ei, const int* __restrict__ flags,
                       const float* __restrict__ dinv, int* __restrict__ pos,
                       int* __restrict__ csr_src, float* __restrict__ csr_w) {
    int e = blockIdx.x * blockDim.x + threadIdx.x;
    if (e >= NE) return;
    int is64 = flags[0];
    int src = ld_idx(ei, (long)e, is64);
    int dst = ld_idx(ei, (long)NE + e, is64);
    int p = atomicAdd(&pos[dst], 1);
    csr_src[p] = src;
    csr_w[p] = dinv[src] * dinv[dst];
}

// Y[n][:] = X[n][:] @ W   (W 128x128 staged in LDS; one wave per node,
// lane l computes cols l and l+64; x row broadcast via shfl)
__global__ __launch_bounds__(256) void k_gemm(const float* __restrict__ X,
                                              const float* __restrict__ W,
                                              float* __restrict__ Y, int nrows) {
    __shared__ float sW[NF * NF];   // 64 KB -> 2 blocks/CU
    int tid = threadIdx.x;
    {
        const float4* W4 = (const float4*)W;
        float4* s4 = (float4*)sW;
        for (int i = tid; i < NF * NF / 4; i += 256) s4[i] = W4[i];
    }
    __syncthreads();
    int wid = tid >> 6, lane = tid & 63;
    for (int n = blockIdx.x * 4 + wid; n < nrows; n += gridDim.x * 4) {
        float2 xv = ((const float2*)(X + (size_t)n * NF))[lane];
        float acc0 = 0.f, acc1 = 0.f;
#pragma unroll
        for (int k = 0; k < NF; k++) {
            float xk = __shfl((k & 1) ? xv.y : xv.x, k >> 1, 64);
            acc0 = fmaf(xk, sW[k * NF + lane], acc0);
            acc1 = fmaf(xk, sW[k * NF + 64 + lane], acc1);
        }
        Y[(size_t)n * NF + lane] = acc0;
        Y[(size_t)n * NF + 64 + lane] = acc1;
    }
}

// OUT[n] = relu( sum_{e in in(n)} XW[src_e]*w_e + XW[n]*dinv[n]^2 + bias )
// one wave per node, float2 per lane (coalesced 512B row reads)
__global__ __launch_bounds__(256) void k_gather(const float* __restrict__ XW,
                                                const int* __restrict__ off,
                                                const int* __restrict__ csr_src,
                                                const float* __restrict__ csr_w,
                                                const float* __restrict__ dinv,
                                                const float* __restrict__ bias,
                                                float* __restrict__ OUT) {
    int wid = threadIdx.x >> 6, lane = threadIdx.x & 63;
    int n = blockIdx.x * 4 + wid;
    if (n >= NN) return;
    int beg = off[n], end = off[n + 1];
    float ax = 0.f, ay = 0.f;
    for (int e = beg; e < end; ++e) {
        int s = csr_src[e];
        float w = csr_w[e];
        float2 v = ((const float2*)(XW + (size_t)s * NF))[lane];
        ax = fmaf(v.x, w, ax);
        ay = fmaf(v.y, w, ay);
    }
    float di = dinv[n];
    float2 sv = ((const float2*)(XW + (size_t)n * NF))[lane];
    float2 bb = ((const float2*)bias)[lane];
    float o0 = fmaxf(ax + sv.x * di * di + bb.x, 0.f);
    float o1 = fmaxf(ay + sv.y * di * di + bb.y, 0.f);
    float2 o = make_float2(o0, o1);
    ((float2*)(OUT + (size_t)n * NF))[lane] = o;
}

__global__ void k_pool(const float* __restrict__ H, const void* __restrict__ batch,
                       const int* __restrict__ flags, float* __restrict__ sums,
                       float* __restrict__ cnt) {
    int t = blockIdx.x * blockDim.x + threadIdx.x;
    int node = t >> 5, q = t & 31;
    if (node >= NN) return;
    int is64 = flags[1];
    int g = ld_idx(batch, (long)node, is64);
    float4 v = ((const float4*)(H + (size_t)node * NF))[q];
    atomicAdd(&sums[g * NF + q * 4 + 0], v.x);
    atomicAdd(&sums[g * NF + q * 4 + 1], v.y);
    atomicAdd(&sums[g * NF + q * 4 + 2], v.z);
    atomicAdd(&sums[g * NF + q * 4 + 3], v.w);
    if (q == 0) atomicAdd(&cnt[g], 1.0f);
}

__global__ void k_final(const float* __restrict__ sums, const float* __restrict__ cnt,
                        const float* __restrict__ Wl, const float* __restrict__ bl,
                        float* __restrict__ out) {
    int t = blockIdx.x * blockDim.x + threadIdx.x;
    if (t >= NG * NC) return;
    int g = t / NC, c = t % NC;
    float ic = 1.0f / fmaxf(cnt[g], 1.0f);
    float acc = bl[c];
#pragma unroll 8
    for (int k = 0; k < NF; k++)
        acc = fmaf(sums[g * NF + k] * ic, Wl[k * NC + c], acc);
    out[g * NC + c] = acc;
}

extern "C" void kernel_launch(void* const* d_in, const int* in_sizes, int n_in,
                              void* d_out, int out_size, void* d_ws, size_t ws_size,
                              hipStream_t stream) {
    const float* x  = (const float*)d_in[0];
    const void*  ei = d_in[1];
    const void*  bt = d_in[2];
    const float* W1 = (const float*)d_in[3];
    const float* b1 = (const float*)d_in[4];
    const float* W2 = (const float*)d_in[5];
    const float* b2 = (const float*)d_in[6];
    const float* Wl = (const float*)d_in[7];
    const float* bl = (const float*)d_in[8];

    char* ws = (char*)d_ws;
    int*   flags = (int*)(ws + 0);
    int*   deg   = (int*)(ws + 16);
    float* sums  = (float*)(ws + 40016);
    float* cnt   = (float*)(ws + 72784);
    int*   coff  = (int*)(ws + 73040);
    int*   cpos  = (int*)(ws + 113056);
    float* dinv  = (float*)(ws + 153056);
    int*   csrc  = (int*)(ws + 193056);
    float* cw    = (float*)(ws + 2753056);
    float* bufA  = (float*)(ws + 5313056);
    float* bufB  = (float*)(ws + 10433056);

    // zero deg + sums + cnt (contiguous region), every launch
    hipMemsetAsync(ws + 16, 0, 73024, stream);

    k_detect<<<1, 256, 0, stream>>>((const int*)ei, (const int*)bt, flags);
    k_degree<<<(NE + 255) / 256, 256, 0, stream>>>(ei, flags, deg);
    k_scan<<<1, 1024, 0, stream>>>(deg, coff, cpos, dinv);
    k_fill<<<(NE + 255) / 256, 256, 0, stream>>>(ei, flags, dinv, cpos, csrc, cw);

    k_gemm<<<512, 256, 0, stream>>>(x, W1, bufA, NN);
    k_gather<<<(NN + 3) / 4, 256, 0, stream>>>(bufA, coff, csrc, cw, dinv, b1, bufB);
    k_gemm<<<512, 256, 0, stream>>>(bufB, W2, bufA, NN);
    k_gather<<<(NN + 3) / 4, 256, 0, stream>>>(bufA, coff, csrc, cw, dinv, b2, bufB);

    k_pool<<<(NN * 32 + 255) / 256, 256, 0, stream>>>(bufB, bt, flags, sums, cnt);
    k_final<<<(NG * NC + 255) / 256, 256, 0, stream>>>(sums, cnt, Wl, bl, (float*)d_out);
}

// Round 2
// 432.944 us; speedup vs baseline: 1.3082x; 1.3082x over previous
//
#include <hip/hip_runtime.h>
#include <hip/hip_bf16.h>

#define NN 10000     // nodes
#define NE 640000    // edges
#define NG 64        // graphs
#define NF 128       // feature dim (both layers)
#define NC 10        // classes
#define NPASS 4      // dst-range passes in k_fill (write-locality)

// ---------------- ws layout (bytes) ----------------
// 0        deg   (10000 int)     40000  } zeroed region (73024 B)
// 40000    sums  (64*128 f32)    32768  }
// 72768    cnt   (64 f32)        256    }
// 73024    coff  (10001 int)     40016
// 113040   cpos  (10000 int)     40000
// 153040   dinv  (10000 f32)     40000
// 193040   csrc  (640000 int)    2560000
// 2753040  bufA  (10000*128 f32) 5120000
// 7873040  bufB  (10000*128 f32) 5120000

// Wave-uniform detection of int64 vs int32 index buffers. For little-endian
// int64, every odd 32-bit word is the (always-zero here) high half. We sample
// 64 odd words spread over the buffer; genuine int32 data (node ids / sorted
// batch ids spanning 64 graphs) cannot have all 64 samples zero.
__device__ __forceinline__ int detect64(const int* w, long span) {
    int lane = threadIdx.x & 63;
    long e = (long)lane * (span - 1) / 63;
    return (__ballot(w[2 * e + 1] != 0) == 0ULL) ? 1 : 0;
}

__device__ __forceinline__ int ld_idx(const void* p, long i, int is64) {
    return is64 ? (int)((const long long*)p)[i] : ((const int*)p)[i];
}

__global__ void k_degree(const void* __restrict__ ei, int* __restrict__ deg) {
    int is64 = detect64((const int*)ei, NE);
    int e = blockIdx.x * blockDim.x + threadIdx.x;
    if (e >= NE) return;
    int dst = ld_idx(ei, (long)NE + e, is64);
    atomicAdd(&deg[dst], 1);
}

// Single-block exclusive scan of deg -> csr_off / csr_pos; dinv = rsqrt(deg+1)
__global__ __launch_bounds__(1024) void k_scan(const int* __restrict__ deg,
                                               int* __restrict__ off, int* __restrict__ pos,
                                               float* __restrict__ dinv) {
    __shared__ int part[1024];
    int tid = threadIdx.x;
    const int CH = 10;              // 1024*10 >= 10000
    int base = tid * CH;
    int s = 0;
#pragma unroll
    for (int i = 0; i < CH; i++) { int id = base + i; if (id < NN) s += deg[id]; }
    part[tid] = s;
    __syncthreads();
    for (int o = 1; o < 1024; o <<= 1) {
        int add = (tid >= o) ? part[tid - o] : 0;
        __syncthreads();
        part[tid] += add;
        __syncthreads();
    }
    int run = (tid > 0) ? part[tid - 1] : 0;
#pragma unroll
    for (int i = 0; i < CH; i++) {
        int id = base + i;
        if (id < NN) { off[id] = run; pos[id] = run; run += deg[id]; }
    }
    if (tid == 0) off[NN] = part[1023];
    for (int id = tid; id < NN; id += 1024)
        dinv[id] = rsqrtf((float)deg[id] + 1.0f);
}

// CSR fill, src-only payload (weights recomputed in gather). NPASS dst-range
// passes confine the scattered stores to a 640 KB window that stays L2-resident
// (vs 11x HBM write amplification from device-wide random 4B stores).
// Grid-stride with a fully co-resident grid keeps passes loosely in lockstep.
__global__ __launch_bounds__(256) void k_fill(const void* __restrict__ ei,
                                              int* __restrict__ pos,
                                              int* __restrict__ csrc) {
    int is64 = detect64((const int*)ei, NE);
    int stride = gridDim.x * blockDim.x;
    int t0 = blockIdx.x * blockDim.x + threadIdx.x;
    for (int pass = 0; pass < NPASS; ++pass) {
        int lo = pass * (NN / NPASS);
        int hi = lo + (NN / NPASS);
        for (int e = t0; e < NE; e += stride) {
            int dst = ld_idx(ei, (long)NE + e, is64);
            if (dst < lo || dst >= hi) continue;
            int src = ld_idx(ei, (long)e, is64);
            int p = atomicAdd(&pos[dst], 1);
            csrc[p] = src;
        }
    }
}

// Y[n][:] = X[n][:] @ W   (W 128x128 staged in LDS; one wave per node,
// lane l computes cols l and l+64; x row broadcast via shfl)
__global__ __launch_bounds__(256) void k_gemm(const float* __restrict__ X,
                                              const float* __restrict__ W,
                                              float* __restrict__ Y, int nrows) {
    __shared__ float sW[NF * NF];
    int tid = threadIdx.x;
    {
        const float4* W4 = (const float4*)W;
        float4* s4 = (float4*)sW;
        for (int i = tid; i < NF * NF / 4; i += 256) s4[i] = W4[i];
    }
    __syncthreads();
    int wid = tid >> 6, lane = tid & 63;
    for (int n = blockIdx.x * 4 + wid; n < nrows; n += gridDim.x * 4) {
        float2 xv = ((const float2*)(X + (size_t)n * NF))[lane];
        float acc0 = 0.f, acc1 = 0.f;
#pragma unroll
        for (int k = 0; k < NF; k++) {
            float xk = __shfl((k & 1) ? xv.y : xv.x, k >> 1, 64);
            acc0 = fmaf(xk, sW[k * NF + lane], acc0);
            acc1 = fmaf(xk, sW[k * NF + 64 + lane], acc1);
        }
        Y[(size_t)n * NF + lane] = acc0;
        Y[(size_t)n * NF + 64 + lane] = acc1;
    }
}

// OUT[n] = relu( sum_{e in in(n)} XW[src_e]*dinv[src_e]*dinv[n]
//                + XW[n]*dinv[n]^2 + bias )
// One wave per node. Lanes 0-31 handle even edges, 32-63 odd edges; each lane
// reads a float4 (16B, coalescing sweet spot). 2-deep unroll -> 4 row reads
// in flight per wave. Halves combined via shfl_xor(32) at the end.
__global__ __launch_bounds__(256) void k_gather(const float* __restrict__ XW,
                                                const int* __restrict__ off,
                                                const int* __restrict__ csrc,
                                                const float* __restrict__ dinv,
                                                const float* __restrict__ bias,
                                                float* __restrict__ OUT) {
    int wid = threadIdx.x >> 6, lane = threadIdx.x & 63;
    int half = lane >> 5;
    int c4 = lane & 31;
    int n = blockIdx.x * 4 + wid;
    if (n >= NN) return;
    int beg = off[n], end = off[n + 1];
    float din = dinv[n];
    float4 acc = make_float4(0.f, 0.f, 0.f, 0.f);
    int e = beg + half;
    for (; e + 2 < end; e += 4) {
        int s0 = csrc[e];
        int s1 = csrc[e + 2];
        float4 v0 = ((const float4*)(XW + (size_t)s0 * NF))[c4];
        float4 v1 = ((const float4*)(XW + (size_t)s1 * NF))[c4];
        float w0 = dinv[s0] * din;
        float w1 = dinv[s1] * din;
        acc.x = fmaf(v0.x, w0, acc.x); acc.y = fmaf(v0.y, w0, acc.y);
        acc.z = fmaf(v0.z, w0, acc.z); acc.w = fmaf(v0.w, w0, acc.w);
        acc.x = fmaf(v1.x, w1, acc.x); acc.y = fmaf(v1.y, w1, acc.y);
        acc.z = fmaf(v1.z, w1, acc.z); acc.w = fmaf(v1.w, w1, acc.w);
    }
    for (; e < end; e += 2) {
        int s = csrc[e];
        float w = dinv[s] * din;
        float4 v = ((const float4*)(XW + (size_t)s * NF))[c4];
        acc.x = fmaf(v.x, w, acc.x); acc.y = fmaf(v.y, w, acc.y);
        acc.z = fmaf(v.z, w, acc.z); acc.w = fmaf(v.w, w, acc.w);
    }
    acc.x += __shfl_xor(acc.x, 32);
    acc.y += __shfl_xor(acc.y, 32);
    acc.z += __shfl_xor(acc.z, 32);
    acc.w += __shfl_xor(acc.w, 32);
    if (half == 0) {
        float4 sv = ((const float4*)(XW + (size_t)n * NF))[c4];
        float4 bb = ((const float4*)bias)[c4];
        float d2 = din * din;
        float4 o;
        o.x = fmaxf(fmaf(sv.x, d2, acc.x) + bb.x, 0.f);
        o.y = fmaxf(fmaf(sv.y, d2, acc.y) + bb.y, 0.f);
        o.z = fmaxf(fmaf(sv.z, d2, acc.z) + bb.z, 0.f);
        o.w = fmaxf(fmaf(sv.w, d2, acc.w) + bb.w, 0.f);
        ((float4*)(OUT + (size_t)n * NF))[c4] = o;
    }
}

__global__ void k_pool(const float* __restrict__ H, const void* __restrict__ batch,
                       float* __restrict__ sums, float* __restrict__ cnt) {
    int is64 = detect64((const int*)batch, NN / 2);
    int t = blockIdx.x * blockDim.x + threadIdx.x;
    int node = t >> 5, q = t & 31;
    if (node >= NN) return;
    int g = ld_idx(batch, (long)node, is64);
    float4 v = ((const float4*)(H + (size_t)node * NF))[q];
    atomicAdd(&sums[g * NF + q * 4 + 0], v.x);
    atomicAdd(&sums[g * NF + q * 4 + 1], v.y);
    atomicAdd(&sums[g * NF + q * 4 + 2], v.z);
    atomicAdd(&sums[g * NF + q * 4 + 3], v.w);
    if (q == 0) atomicAdd(&cnt[g], 1.0f);
}

__global__ void k_final(const float* __restrict__ sums, const float* __restrict__ cnt,
                        const float* __restrict__ Wl, const float* __restrict__ bl,
                        float* __restrict__ out) {
    int t = blockIdx.x * blockDim.x + threadIdx.x;
    if (t >= NG * NC) return;
    int g = t / NC, c = t % NC;
    float ic = 1.0f / fmaxf(cnt[g], 1.0f);
    float acc = bl[c];
#pragma unroll 8
    for (int k = 0; k < NF; k++)
        acc = fmaf(sums[g * NF + k] * ic, Wl[k * NC + c], acc);
    out[g * NC + c] = acc;
}

extern "C" void kernel_launch(void* const* d_in, const int* in_sizes, int n_in,
                              void* d_out, int out_size, void* d_ws, size_t ws_size,
                              hipStream_t stream) {
    const float* x  = (const float*)d_in[0];
    const void*  ei = d_in[1];
    const void*  bt = d_in[2];
    const float* W1 = (const float*)d_in[3];
    const float* b1 = (const float*)d_in[4];
    const float* W2 = (const float*)d_in[5];
    const float* b2 = (const float*)d_in[6];
    const float* Wl = (const float*)d_in[7];
    const float* bl = (const float*)d_in[8];

    char* ws = (char*)d_ws;
    int*   deg   = (int*)(ws + 0);
    float* sums  = (float*)(ws + 40000);
    float* cnt   = (float*)(ws + 72768);
    int*   coff  = (int*)(ws + 73024);
    int*   cpos  = (int*)(ws + 113040);
    float* dinv  = (float*)(ws + 153040);
    int*   csrc  = (int*)(ws + 193040);
    float* bufA  = (float*)(ws + 2753040);
    float* bufB  = (float*)(ws + 7873040);

    hipMemsetAsync(ws, 0, 73024, stream);   // deg + sums + cnt

    k_degree<<<(NE + 255) / 256, 256, 0, stream>>>(ei, deg);
    k_scan<<<1, 1024, 0, stream>>>(deg, coff, cpos, dinv);
    k_fill<<<2048, 256, 0, stream>>>(ei, cpos, csrc);

    k_gemm<<<512, 256, 0, stream>>>(x, W1, bufA, NN);
    k_gather<<<(NN + 3) / 4, 256, 0, stream>>>(bufA, coff, csrc, dinv, b1, bufB);
    k_gemm<<<512, 256, 0, stream>>>(bufB, W2, bufA, NN);
    k_gather<<<(NN + 3) / 4, 256, 0, stream>>>(bufA, coff, csrc, dinv, b2, bufB);

    k_pool<<<(NN * 32 + 255) / 256, 256, 0, stream>>>(bufB, bt, sums, cnt);
    k_final<<<(NG * NC + 255) / 256, 256, 0, stream>>>(sums, cnt, Wl, bl, (float*)d_out);
}

// Round 3
// 370.697 us; speedup vs baseline: 1.5279x; 1.1679x over previous
//
#include <hip/hip_runtime.h>
#include <hip/hip_bf16.h>

#define NN 10000     // nodes
#define NE 640000    // edges
#define NG 64        // graphs
#define NF 128       // feature dim (both layers)
#define NC 10        // classes
#define NPASS 4      // dst-range passes in k_fill (write-locality)

// ---------------- ws layout (bytes) ----------------
// 0        deg   (10000 int)     40000  } zeroed every launch
// 73024    coff  (10001 int)     40016
// 113040   cpos  (10000 int)     40000
// 153040   dinv  (10000 f32)     40000
// 193040   csrc  (640000 int)    2560000
// 2753040  bufA  (10000*128 f32) 5120000
// 7873040  bufB  (10000*128 f32) 5120000

// Wave-uniform detection of int64 vs int32 index buffers. For little-endian
// int64, every odd 32-bit word is the (always-zero here) high half.
__device__ __forceinline__ int detect64(const int* w, long span) {
    int lane = threadIdx.x & 63;
    long e = (long)lane * (span - 1) / 63;
    return (__ballot(w[2 * e + 1] != 0) == 0ULL) ? 1 : 0;
}

__device__ __forceinline__ int ld_idx(const void* p, long i, int is64) {
    return is64 ? (int)((const long long*)p)[i] : ((const int*)p)[i];
}

__global__ void k_degree(const void* __restrict__ ei, int* __restrict__ deg) {
    int is64 = detect64((const int*)ei, NE);
    int e = blockIdx.x * blockDim.x + threadIdx.x;
    if (e >= NE) return;
    int dst = ld_idx(ei, (long)NE + e, is64);
    atomicAdd(&deg[dst], 1);
}

// Single-block exclusive scan of deg -> csr_off / csr_pos; dinv = rsqrt(deg+1)
__global__ __launch_bounds__(1024) void k_scan(const int* __restrict__ deg,
                                               int* __restrict__ off, int* __restrict__ pos,
                                               float* __restrict__ dinv) {
    __shared__ int part[1024];
    int tid = threadIdx.x;
    const int CH = 10;              // 1024*10 >= 10000
    int base = tid * CH;
    int s = 0;
#pragma unroll
    for (int i = 0; i < CH; i++) { int id = base + i; if (id < NN) s += deg[id]; }
    part[tid] = s;
    __syncthreads();
    for (int o = 1; o < 1024; o <<= 1) {
        int add = (tid >= o) ? part[tid - o] : 0;
        __syncthreads();
        part[tid] += add;
        __syncthreads();
    }
    int run = (tid > 0) ? part[tid - 1] : 0;
#pragma unroll
    for (int i = 0; i < CH; i++) {
        int id = base + i;
        if (id < NN) { off[id] = run; pos[id] = run; run += deg[id]; }
    }
    if (tid == 0) off[NN] = part[1023];
    for (int id = tid; id < NN; id += 1024)
        dinv[id] = rsqrtf((float)deg[id] + 1.0f);
}

// CSR fill, src-only payload (weights recomputed in gather). NPASS dst-range
// passes confine the scattered stores to an L2-resident window.
__global__ __launch_bounds__(256) void k_fill(const void* __restrict__ ei,
                                              int* __restrict__ pos,
                                              int* __restrict__ csrc) {
    int is64 = detect64((const int*)ei, NE);
    int stride = gridDim.x * blockDim.x;
    int t0 = blockIdx.x * blockDim.x + threadIdx.x;
    for (int pass = 0; pass < NPASS; ++pass) {
        int lo = pass * (NN / NPASS);
        int hi = lo + (NN / NPASS);
        for (int e = t0; e < NE; e += stride) {
            int dst = ld_idx(ei, (long)NE + e, is64);
            if (dst < lo || dst >= hi) continue;
            int src = ld_idx(ei, (long)e, is64);
            int p = atomicAdd(&pos[dst], 1);
            csrc[p] = src;
        }
    }
}

// Y[n][:] = X[n][:] @ W   (W 128x128 staged in LDS; one wave per node)
__global__ __launch_bounds__(256) void k_gemm(const float* __restrict__ X,
                                              const float* __restrict__ W,
                                              float* __restrict__ Y, int nrows) {
    __shared__ float sW[NF * NF];
    int tid = threadIdx.x;
    {
        const float4* W4 = (const float4*)W;
        float4* s4 = (float4*)sW;
        for (int i = tid; i < NF * NF / 4; i += 256) s4[i] = W4[i];
    }
    __syncthreads();
    int wid = tid >> 6, lane = tid & 63;
    for (int n = blockIdx.x * 4 + wid; n < nrows; n += gridDim.x * 4) {
        float2 xv = ((const float2*)(X + (size_t)n * NF))[lane];
        float acc0 = 0.f, acc1 = 0.f;
#pragma unroll
        for (int k = 0; k < NF; k++) {
            float xk = __shfl((k & 1) ? xv.y : xv.x, k >> 1, 64);
            acc0 = fmaf(xk, sW[k * NF + lane], acc0);
            acc1 = fmaf(xk, sW[k * NF + 64 + lane], acc1);
        }
        Y[(size_t)n * NF + lane] = acc0;
        Y[(size_t)n * NF + 64 + lane] = acc1;
    }
}

// OUT[n] = relu( sum_{e in in(n)} XW[src_e]*dinv[src_e]*dinv[n]
//                + XW[n]*dinv[n]^2 + bias )
// One wave per node; half-wave per edge; float4 per lane.
__global__ __launch_bounds__(256) void k_gather(const float* __restrict__ XW,
                                                const int* __restrict__ off,
                                                const int* __restrict__ csrc,
                                                const float* __restrict__ dinv,
                                                const float* __restrict__ bias,
                                                float* __restrict__ OUT) {
    int wid = threadIdx.x >> 6, lane = threadIdx.x & 63;
    int half = lane >> 5;
    int c4 = lane & 31;
    int n = blockIdx.x * 4 + wid;
    if (n >= NN) return;
    int beg = off[n], end = off[n + 1];
    float din = dinv[n];
    float4 acc = make_float4(0.f, 0.f, 0.f, 0.f);
    int e = beg + half;
    for (; e + 2 < end; e += 4) {
        int s0 = csrc[e];
        int s1 = csrc[e + 2];
        float4 v0 = ((const float4*)(XW + (size_t)s0 * NF))[c4];
        float4 v1 = ((const float4*)(XW + (size_t)s1 * NF))[c4];
        float w0 = dinv[s0] * din;
        float w1 = dinv[s1] * din;
        acc.x = fmaf(v0.x, w0, acc.x); acc.y = fmaf(v0.y, w0, acc.y);
        acc.z = fmaf(v0.z, w0, acc.z); acc.w = fmaf(v0.w, w0, acc.w);
        acc.x = fmaf(v1.x, w1, acc.x); acc.y = fmaf(v1.y, w1, acc.y);
        acc.z = fmaf(v1.z, w1, acc.z); acc.w = fmaf(v1.w, w1, acc.w);
    }
    for (; e < end; e += 2) {
        int s = csrc[e];
        float w = dinv[s] * din;
        float4 v = ((const float4*)(XW + (size_t)s * NF))[c4];
        acc.x = fmaf(v.x, w, acc.x); acc.y = fmaf(v.y, w, acc.y);
        acc.z = fmaf(v.z, w, acc.z); acc.w = fmaf(v.w, w, acc.w);
    }
    acc.x += __shfl_xor(acc.x, 32);
    acc.y += __shfl_xor(acc.y, 32);
    acc.z += __shfl_xor(acc.z, 32);
    acc.w += __shfl_xor(acc.w, 32);
    if (half == 0) {
        float4 sv = ((const float4*)(XW + (size_t)n * NF))[c4];
        float4 bb = ((const float4*)bias)[c4];
        float d2 = din * din;
        float4 o;
        o.x = fmaxf(fmaf(sv.x, d2, acc.x) + bb.x, 0.f);
        o.y = fmaxf(fmaf(sv.y, d2, acc.y) + bb.y, 0.f);
        o.z = fmaxf(fmaf(sv.z, d2, acc.z) + bb.z, 0.f);
        o.w = fmaxf(fmaf(sv.w, d2, acc.w) + bb.w, 0.f);
        ((float4*)(OUT + (size_t)n * NF))[c4] = o;
    }
}

// Fused global-mean-pool + final linear. batch is SORTED (jnp.sort in setup),
// so each graph's nodes are a contiguous row range -> segmented sum, zero
// atomics. One block per graph: binary-search the range, float4 row sweep
// (8 rows in flight across 256 threads), LDS reduce, then 10-class dot.
__global__ __launch_bounds__(256) void k_poolfin(const float* __restrict__ H,
                                                 const void* __restrict__ batch,
                                                 const float* __restrict__ Wl,
                                                 const float* __restrict__ bl,
                                                 float* __restrict__ out) {
    int is64 = detect64((const int*)batch, NN / 2);
    __shared__ int sb[2];
    __shared__ float4 part[256];
    __shared__ float pooled[NF];
    int g = blockIdx.x;
    int tid = threadIdx.x;
    if (tid < 2) {
        int target = g + tid;                 // lower_bound(batch, target)
        int lo = 0, hi = NN;
        while (lo < hi) {
            int mid = (lo + hi) >> 1;
            if (ld_idx(batch, mid, is64) < target) lo = mid + 1; else hi = mid;
        }
        sb[tid] = lo;
    }
    __syncthreads();
    int beg = sb[0], end = sb[1];
    int c4 = tid & 31, r = tid >> 5;          // 8 rows in flight
    float4 acc = make_float4(0.f, 0.f, 0.f, 0.f);
    for (int n = beg + r; n < end; n += 8) {
        float4 v = ((const float4*)(H + (size_t)n * NF))[c4];
        acc.x += v.x; acc.y += v.y; acc.z += v.z; acc.w += v.w;
    }
    part[tid] = acc;
    __syncthreads();
    if (tid < 32) {
        float4 s = part[tid];
#pragma unroll
        for (int j = 1; j < 8; j++) {
            float4 p = part[tid + 32 * j];
            s.x += p.x; s.y += p.y; s.z += p.z; s.w += p.w;
        }
        float ic = 1.0f / fmaxf((float)(end - beg), 1.0f);
        pooled[tid * 4 + 0] = s.x * ic;
        pooled[tid * 4 + 1] = s.y * ic;
        pooled[tid * 4 + 2] = s.z * ic;
        pooled[tid * 4 + 3] = s.w * ic;
    }
    __syncthreads();
    if (tid < NC) {
        float a = bl[tid];
#pragma unroll 8
        for (int k = 0; k < NF; k++)
            a = fmaf(pooled[k], Wl[k * NC + tid], a);
        out[g * NC + tid] = a;
    }
}

extern "C" void kernel_launch(void* const* d_in, const int* in_sizes, int n_in,
                              void* d_out, int out_size, void* d_ws, size_t ws_size,
                              hipStream_t stream) {
    const float* x  = (const float*)d_in[0];
    const void*  ei = d_in[1];
    const void*  bt = d_in[2];
    const float* W1 = (const float*)d_in[3];
    const float* b1 = (const float*)d_in[4];
    const float* W2 = (const float*)d_in[5];
    const float* b2 = (const float*)d_in[6];
    const float* Wl = (const float*)d_in[7];
    const float* bl = (const float*)d_in[8];

    char* ws = (char*)d_ws;
    int*   deg   = (int*)(ws + 0);
    int*   coff  = (int*)(ws + 73024);
    int*   cpos  = (int*)(ws + 113040);
    float* dinv  = (float*)(ws + 153040);
    int*   csrc  = (int*)(ws + 193040);
    float* bufA  = (float*)(ws + 2753040);
    float* bufB  = (float*)(ws + 7873040);

    hipMemsetAsync(ws, 0, 40000, stream);   // deg only

    k_degree<<<(NE + 255) / 256, 256, 0, stream>>>(ei, deg);
    k_scan<<<1, 1024, 0, stream>>>(deg, coff, cpos, dinv);
    k_fill<<<2048, 256, 0, stream>>>(ei, cpos, csrc);

    k_gemm<<<512, 256, 0, stream>>>(x, W1, bufA, NN);
    k_gather<<<(NN + 3) / 4, 256, 0, stream>>>(bufA, coff, csrc, dinv, b1, bufB);
    k_gemm<<<512, 256, 0, stream>>>(bufB, W2, bufA, NN);
    k_gather<<<(NN + 3) / 4, 256, 0, stream>>>(bufA, coff, csrc, dinv, b2, bufB);

    k_poolfin<<<NG, 256, 0, stream>>>(bufB, bt, Wl, bl, (float*)d_out);
}

// Round 4
// 285.891 us; speedup vs baseline: 1.9812x; 1.2966x over previous
//
#include <hip/hip_runtime.h>
#include <hip/hip_bf16.h>

#define NN 10000     // nodes
#define NE 640000    // edges
#define NG 64        // graphs
#define NF 128       // feature dim (both layers)
#define NC 10        // classes
#define NPASS 4      // dst-range passes in k_fill (write-locality)
#define TM 32        // gemm row tile
#define TKC 32       // gemm k chunk

// ---------------- ws layout (bytes) ----------------
// 0        deg   (10000 int)     40000  } zeroed every launch
// 73024    coff  (10001 int)     40016
// 113040   cpos  (10000 int)     40000
// 153040   dinv  (10000 f32)     40000
// 193040   csrc  (640000 int)    2560000
// 2753040  bufA  (10000*128 f32) 5120000
// 7873040  bufB  (10000*128 f32) 5120000

// Wave-uniform detection of int64 vs int32 index buffers. For little-endian
// int64, every odd 32-bit word is the (always-zero here) high half.
__device__ __forceinline__ int detect64(const int* w, long span) {
    int lane = threadIdx.x & 63;
    long e = (long)lane * (span - 1) / 63;
    return (__ballot(w[2 * e + 1] != 0) == 0ULL) ? 1 : 0;
}

__device__ __forceinline__ int ld_idx(const void* p, long i, int is64) {
    return is64 ? (int)((const long long*)p)[i] : ((const int*)p)[i];
}

__global__ void k_degree(const void* __restrict__ ei, int* __restrict__ deg) {
    int is64 = detect64((const int*)ei, NE);
    int e = blockIdx.x * blockDim.x + threadIdx.x;
    if (e >= NE) return;
    int dst = ld_idx(ei, (long)NE + e, is64);
    atomicAdd(&deg[dst], 1);
}

// Single-block exclusive scan of deg -> csr_off / csr_pos; dinv = rsqrt(deg+1)
__global__ __launch_bounds__(1024) void k_scan(const int* __restrict__ deg,
                                               int* __restrict__ off, int* __restrict__ pos,
                                               float* __restrict__ dinv) {
    __shared__ int part[1024];
    int tid = threadIdx.x;
    const int CH = 10;              // 1024*10 >= 10000
    int base = tid * CH;
    int s = 0;
#pragma unroll
    for (int i = 0; i < CH; i++) { int id = base + i; if (id < NN) s += deg[id]; }
    part[tid] = s;
    __syncthreads();
    for (int o = 1; o < 1024; o <<= 1) {
        int add = (tid >= o) ? part[tid - o] : 0;
        __syncthreads();
        part[tid] += add;
        __syncthreads();
    }
    int run = (tid > 0) ? part[tid - 1] : 0;
#pragma unroll
    for (int i = 0; i < CH; i++) {
        int id = base + i;
        if (id < NN) { off[id] = run; pos[id] = run; run += deg[id]; }
    }
    if (tid == 0) off[NN] = part[1023];
    for (int id = tid; id < NN; id += 1024)
        dinv[id] = rsqrtf((float)deg[id] + 1.0f);
}

// CSR fill, src-only payload (weights recomputed in gather). NPASS dst-range
// passes confine the scattered stores to an L2-resident window.
__global__ __launch_bounds__(256) void k_fill(const void* __restrict__ ei,
                                              int* __restrict__ pos,
                                              int* __restrict__ csrc) {
    int is64 = detect64((const int*)ei, NE);
    int stride = gridDim.x * blockDim.x;
    int t0 = blockIdx.x * blockDim.x + threadIdx.x;
    for (int pass = 0; pass < NPASS; ++pass) {
        int lo = pass * (NN / NPASS);
        int hi = lo + (NN / NPASS);
        for (int e = t0; e < NE; e += stride) {
            int dst = ld_idx(ei, (long)NE + e, is64);
            if (dst < lo || dst >= hi) continue;
            int src = ld_idx(ei, (long)e, is64);
            int p = atomicAdd(&pos[dst], 1);
            csrc[p] = src;
        }
    }
}

// Y = X @ W, register-tiled. Block: 256 thr, 32 rows x 128 cols.
// Thread: 4x4 acc. X staged transposed in LDS ([k][m], stride 36); W staged
// in 32 column-panels (panel cg = cols 4cg..4cg+3 over k, stride 132) so the
// per-k ds_read_b128s from the 8 row/col-groups of a wave land on disjoint
// bank quads (conflict-free). 2 LDS ops per 16 FMA. K strictly in-order ->
// bit-identical accumulation vs the reference order.
__global__ __launch_bounds__(256) void k_gemm(const float* __restrict__ X,
                                              const float* __restrict__ W,
                                              float* __restrict__ Y, int nrows) {
    __shared__ float sX[TKC * 36];       // 4.6 KB
    __shared__ float sW[32 * 132];       // 16.9 KB
    int tid = threadIdx.x;
    int rg = tid & 7;                    // rows rg*4 .. rg*4+3
    int cg = tid >> 3;                   // cols cg*4 .. cg*4+3 (0..31)
    int m0 = blockIdx.x * TM;
    float acc[4][4] = {{0.f}};
    for (int kc = 0; kc < NF / TKC; ++kc) {
        int k0 = kc * TKC;
        {   // stage X^T (one float4 per thread)
            int row = tid >> 3, kq = tid & 7;
            int mm = m0 + row; if (mm > nrows - 1) mm = nrows - 1;
            float4 v = *(const float4*)(X + (size_t)mm * NF + k0 + kq * 4);
            sX[(kq * 4 + 0) * 36 + row] = v.x;
            sX[(kq * 4 + 1) * 36 + row] = v.y;
            sX[(kq * 4 + 2) * 36 + row] = v.z;
            sX[(kq * 4 + 3) * 36 + row] = v.w;
        }
#pragma unroll
        for (int j = 0; j < 4; ++j) {    // stage W panels (4 float4 per thread)
            int idx = tid + 256 * j;
            int k = idx >> 5, cq = idx & 31;
            float4 v = *(const float4*)(W + (size_t)(k0 + k) * NF + cq * 4);
            *(float4*)(sW + cq * 132 + k * 4) = v;
        }
        __syncthreads();
#pragma unroll 8
        for (int k = 0; k < TKC; ++k) {
            float4 xf = *(const float4*)(sX + k * 36 + rg * 4);
            float4 wf = *(const float4*)(sW + cg * 132 + k * 4);
            acc[0][0] = fmaf(xf.x, wf.x, acc[0][0]);
            acc[0][1] = fmaf(xf.x, wf.y, acc[0][1]);
            acc[0][2] = fmaf(xf.x, wf.z, acc[0][2]);
            acc[0][3] = fmaf(xf.x, wf.w, acc[0][3]);
            acc[1][0] = fmaf(xf.y, wf.x, acc[1][0]);
            acc[1][1] = fmaf(xf.y, wf.y, acc[1][1]);
            acc[1][2] = fmaf(xf.y, wf.z, acc[1][2]);
            acc[1][3] = fmaf(xf.y, wf.w, acc[1][3]);
            acc[2][0] = fmaf(xf.z, wf.x, acc[2][0]);
            acc[2][1] = fmaf(xf.z, wf.y, acc[2][1]);
            acc[2][2] = fmaf(xf.z, wf.z, acc[2][2]);
            acc[2][3] = fmaf(xf.z, wf.w, acc[2][3]);
            acc[3][0] = fmaf(xf.w, wf.x, acc[3][0]);
            acc[3][1] = fmaf(xf.w, wf.y, acc[3][1]);
            acc[3][2] = fmaf(xf.w, wf.z, acc[3][2]);
            acc[3][3] = fmaf(xf.w, wf.w, acc[3][3]);
        }
        __syncthreads();
    }
#pragma unroll
    for (int r = 0; r < 4; ++r) {
        int m = m0 + rg * 4 + r;
        if (m < nrows)
            *(float4*)(Y + (size_t)m * NF + cg * 4) =
                make_float4(acc[r][0], acc[r][1], acc[r][2], acc[r][3]);
    }
}

// OUT[n] = relu( sum_{e in in(n)} XW[src_e]*dinv[src_e]*dinv[n]
//                + XW[n]*dinv[n]^2 + bias )
// One wave per node; half-wave per edge; float4 per lane.
__global__ __launch_bounds__(256) void k_gather(const float* __restrict__ XW,
                                                const int* __restrict__ off,
                                                const int* __restrict__ csrc,
                                                const float* __restrict__ dinv,
                                                const float* __restrict__ bias,
                                                float* __restrict__ OUT) {
    int wid = threadIdx.x >> 6, lane = threadIdx.x & 63;
    int half = lane >> 5;
    int c4 = lane & 31;
    int n = blockIdx.x * 4 + wid;
    if (n >= NN) return;
    int beg = off[n], end = off[n + 1];
    float din = dinv[n];
    float4 acc = make_float4(0.f, 0.f, 0.f, 0.f);
    int e = beg + half;
    for (; e + 2 < end; e += 4) {
        int s0 = csrc[e];
        int s1 = csrc[e + 2];
        float4 v0 = ((const float4*)(XW + (size_t)s0 * NF))[c4];
        float4 v1 = ((const float4*)(XW + (size_t)s1 * NF))[c4];
        float w0 = dinv[s0] * din;
        float w1 = dinv[s1] * din;
        acc.x = fmaf(v0.x, w0, acc.x); acc.y = fmaf(v0.y, w0, acc.y);
        acc.z = fmaf(v0.z, w0, acc.z); acc.w = fmaf(v0.w, w0, acc.w);
        acc.x = fmaf(v1.x, w1, acc.x); acc.y = fmaf(v1.y, w1, acc.y);
        acc.z = fmaf(v1.z, w1, acc.z); acc.w = fmaf(v1.w, w1, acc.w);
    }
    for (; e < end; e += 2) {
        int s = csrc[e];
        float w = dinv[s] * din;
        float4 v = ((const float4*)(XW + (size_t)s * NF))[c4];
        acc.x = fmaf(v.x, w, acc.x); acc.y = fmaf(v.y, w, acc.y);
        acc.z = fmaf(v.z, w, acc.z); acc.w = fmaf(v.w, w, acc.w);
    }
    acc.x += __shfl_xor(acc.x, 32);
    acc.y += __shfl_xor(acc.y, 32);
    acc.z += __shfl_xor(acc.z, 32);
    acc.w += __shfl_xor(acc.w, 32);
    if (half == 0) {
        float4 sv = ((const float4*)(XW + (size_t)n * NF))[c4];
        float4 bb = ((const float4*)bias)[c4];
        float d2 = din * din;
        float4 o;
        o.x = fmaxf(fmaf(sv.x, d2, acc.x) + bb.x, 0.f);
        o.y = fmaxf(fmaf(sv.y, d2, acc.y) + bb.y, 0.f);
        o.z = fmaxf(fmaf(sv.z, d2, acc.z) + bb.z, 0.f);
        o.w = fmaxf(fmaf(sv.w, d2, acc.w) + bb.w, 0.f);
        ((float4*)(OUT + (size_t)n * NF))[c4] = o;
    }
}

// Fused global-mean-pool + final linear (batch is sorted -> contiguous ranges).
__global__ __launch_bounds__(256) void k_poolfin(const float* __restrict__ H,
                                                 const void* __restrict__ batch,
                                                 const float* __restrict__ Wl,
                                                 const float* __restrict__ bl,
                                                 float* __restrict__ out) {
    int is64 = detect64((const int*)batch, NN / 2);
    __shared__ int sb[2];
    __shared__ float4 part[256];
    __shared__ float pooled[NF];
    int g = blockIdx.x;
    int tid = threadIdx.x;
    if (tid < 2) {
        int target = g + tid;                 // lower_bound(batch, target)
        int lo = 0, hi = NN;
        while (lo < hi) {
            int mid = (lo + hi) >> 1;
            if (ld_idx(batch, mid, is64) < target) lo = mid + 1; else hi = mid;
        }
        sb[tid] = lo;
    }
    __syncthreads();
    int beg = sb[0], end = sb[1];
    int c4 = tid & 31, r = tid >> 5;          // 8 rows in flight
    float4 acc = make_float4(0.f, 0.f, 0.f, 0.f);
    for (int n = beg + r; n < end; n += 8) {
        float4 v = ((const float4*)(H + (size_t)n * NF))[c4];
        acc.x += v.x; acc.y += v.y; acc.z += v.z; acc.w += v.w;
    }
    part[tid] = acc;
    __syncthreads();
    if (tid < 32) {
        float4 s = part[tid];
#pragma unroll
        for (int j = 1; j < 8; j++) {
            float4 p = part[tid + 32 * j];
            s.x += p.x; s.y += p.y; s.z += p.z; s.w += p.w;
        }
        float ic = 1.0f / fmaxf((float)(end - beg), 1.0f);
        pooled[tid * 4 + 0] = s.x * ic;
        pooled[tid * 4 + 1] = s.y * ic;
        pooled[tid * 4 + 2] = s.z * ic;
        pooled[tid * 4 + 3] = s.w * ic;
    }
    __syncthreads();
    if (tid < NC) {
        float a = bl[tid];
#pragma unroll 8
        for (int k = 0; k < NF; k++)
            a = fmaf(pooled[k], Wl[k * NC + tid], a);
        out[g * NC + tid] = a;
    }
}

extern "C" void kernel_launch(void* const* d_in, const int* in_sizes, int n_in,
                              void* d_out, int out_size, void* d_ws, size_t ws_size,
                              hipStream_t stream) {
    const float* x  = (const float*)d_in[0];
    const void*  ei = d_in[1];
    const void*  bt = d_in[2];
    const float* W1 = (const float*)d_in[3];
    const float* b1 = (const float*)d_in[4];
    const float* W2 = (const float*)d_in[5];
    const float* b2 = (const float*)d_in[6];
    const float* Wl = (const float*)d_in[7];
    const float* bl = (const float*)d_in[8];

    char* ws = (char*)d_ws;
    int*   deg   = (int*)(ws + 0);
    int*   coff  = (int*)(ws + 73024);
    int*   cpos  = (int*)(ws + 113040);
    float* dinv  = (float*)(ws + 153040);
    int*   csrc  = (int*)(ws + 193040);
    float* bufA  = (float*)(ws + 2753040);
    float* bufB  = (float*)(ws + 7873040);

    hipMemsetAsync(ws, 0, 40000, stream);   // deg only

    k_degree<<<(NE + 255) / 256, 256, 0, stream>>>(ei, deg);
    k_scan<<<1, 1024, 0, stream>>>(deg, coff, cpos, dinv);
    k_fill<<<2048, 256, 0, stream>>>(ei, cpos, csrc);

    k_gemm<<<(NN + TM - 1) / TM, 256, 0, stream>>>(x, W1, bufA, NN);
    k_gather<<<(NN + 3) / 4, 256, 0, stream>>>(bufA, coff, csrc, dinv, b1, bufB);
    k_gemm<<<(NN + TM - 1) / TM, 256, 0, stream>>>(bufB, W2, bufA, NN);
    k_gather<<<(NN + 3) / 4, 256, 0, stream>>>(bufA, coff, csrc, dinv, b2, bufB);

    k_poolfin<<<NG, 256, 0, stream>>>(bufB, bt, Wl, bl, (float*)d_out);
}